// Round 7
// baseline (124.940 us; speedup 1.0000x reference)
//
#include <hip/hip_runtime.h>
#include <hip/hip_fp16.h>
#include <math.h>

// floss: weighted BCE with per-batch argmax-centroid weights.
// input/target: [256, 1, 224, 224] fp32. Output: scalar fp32 mean.
//
// R7: single memory phase. The BCE log terms don't depend on the centroid —
// only the weight does. Phase A streams BOTH t and p (103 MB, one max-MLP
// BW-bound phase), computes argmax stats AND the unweighted
// bce2 = l1p2 + t*(lp2-l1p2) (log2 domain; transcendentals hidden under
// memory latency), stashing bce2 as fp16 in 98 KB dynamic LDS (two stride-1
// half2 regions = conflict-free). Phase B is LDS-only: weight = sqrt+rcp per
// element, ~2 us. t stays exact fp32 (better than R6's fp8); fp16 bce2 error
// on the scalar mean ~7e-4 << 5.7e-2. R6 (two global phases) was ~35 us vs
// a ~16 us single-stream floor; this removes all post-barrier global reads.

#define WIMG 224
#define WW (WIMG * WIMG)        // 50176
#define NQ (WW / 4)             // 12544 quads; 56 quads/row
#define NB 256
#define NT 1024
#define NIT (NQ / NT)           // 12 full iterations
#define REM (NQ - NIT * NT)     // 256 tail quads
#define LDS_BYTES (2 * NQ * 4)  // 2 half2 per quad = 100352 B dynamic LDS
#define LN2 0.69314718055994530942f
#define CLAMP2 (-144.269504088896340736f)   // -100/ln2 (log2-domain clamp)

__device__ __forceinline__ void stat_upd(float val, float fi, float fj,
                                         float& m, float& cnt, float& si, float& sj)
{
    bool gt = val > m;
    bool eq = val == m;
    cnt = gt ? 1.0f : (cnt + (eq ? 1.0f : 0.0f));
    si  = gt ? fi   : (si  + (eq ? fi   : 0.0f));
    sj  = gt ? fj   : (sj  + (eq ? fj   : 0.0f));
    m   = fmaxf(m, val);
}

__device__ __forceinline__ float bce2_elem(float p, float t)
{
    float lp2  = fmaxf(__builtin_amdgcn_logf(p),        CLAMP2);
    float l1p2 = fmaxf(__builtin_amdgcn_logf(1.0f - p), CLAMP2);
    return l1p2 + t * (lp2 - l1p2);      // negative; |.| <= 13.3 for these inputs
}

__global__ __launch_bounds__(NT, 4) void floss_kernel(
    const float* __restrict__ input,
    const float* __restrict__ target,
    float* __restrict__ out,
    float inv_total)
{
    extern __shared__ __half2 bce_lds[];     // [0..NQ): elems 0,1; [NQ..2NQ): elems 2,3
    const int b   = blockIdx.x;
    const int tid = threadIdx.x;
    const float4* __restrict__ t4 = (const float4*)(target + (size_t)b * WW);
    const float4* __restrict__ p4 = (const float4*)(input  + (size_t)b * WW);

    // ---- Phase A: one pass over t AND p: stats + unweighted bce2 -> LDS ----
    float m = -1.0f, cnt = 0.0f, si = 0.0f, sj = 0.0f;
    #pragma unroll 4
    for (int it = 0; it < NIT; ++it) {
        int q = it * NT + tid;
        float4 tv = t4[q];
        float4 pv = p4[q];
        int i  = q / 56;
        int j0 = (q - i * 56) * 4;
        float fi = (float)i;
        stat_upd(tv.x, fi, (float)(j0 + 0), m, cnt, si, sj);
        stat_upd(tv.y, fi, (float)(j0 + 1), m, cnt, si, sj);
        stat_upd(tv.z, fi, (float)(j0 + 2), m, cnt, si, sj);
        stat_upd(tv.w, fi, (float)(j0 + 3), m, cnt, si, sj);
        float b0 = bce2_elem(pv.x, tv.x);
        float b1 = bce2_elem(pv.y, tv.y);
        float b2 = bce2_elem(pv.z, tv.z);
        float b3 = bce2_elem(pv.w, tv.w);
        bce_lds[q]      = __floats2half2_rn(b0, b1);
        bce_lds[NQ + q] = __floats2half2_rn(b2, b3);
    }
    const bool has_tail = tid < REM;
    const int qt = NIT * NT + tid;           // tail quad (rows 219..223)
    if (has_tail) {
        float4 tv = t4[qt];
        float4 pv = p4[qt];
        int i  = qt / 56;
        int j0 = (qt - i * 56) * 4;
        float fi = (float)i;
        stat_upd(tv.x, fi, (float)(j0 + 0), m, cnt, si, sj);
        stat_upd(tv.y, fi, (float)(j0 + 1), m, cnt, si, sj);
        stat_upd(tv.z, fi, (float)(j0 + 2), m, cnt, si, sj);
        stat_upd(tv.w, fi, (float)(j0 + 3), m, cnt, si, sj);
        bce_lds[qt]      = __floats2half2_rn(bce2_elem(pv.x, tv.x), bce2_elem(pv.y, tv.y));
        bce_lds[NQ + qt] = __floats2half2_rn(bce2_elem(pv.z, tv.z), bce2_elem(pv.w, tv.w));
    }

    // ---- argmax-stat reduction -> centroid (x, y) ----
    #pragma unroll
    for (int off = 32; off > 0; off >>= 1) {
        float m2  = __shfl_down(m,   off);
        float c2  = __shfl_down(cnt, off);
        float si2 = __shfl_down(si,  off);
        float sj2 = __shfl_down(sj,  off);
        bool gt = m2 > m, eq = m2 == m;
        cnt = gt ? c2  : (cnt + (eq ? c2  : 0.0f));
        si  = gt ? si2 : (si  + (eq ? si2 : 0.0f));
        sj  = gt ? sj2 : (sj  + (eq ? sj2 : 0.0f));
        m   = fmaxf(m, m2);
    }
    __shared__ float sm[16], sc[16], ssi[16], ssj[16];
    __shared__ float sxy[2];
    const int lane = tid & 63, wid = tid >> 6;
    if (lane == 0) { sm[wid] = m; sc[wid] = cnt; ssi[wid] = si; ssj[wid] = sj; }
    __syncthreads();
    if (tid == 0) {
        float M = sm[0], C = sc[0], SI = ssi[0], SJ = ssj[0];
        #pragma unroll
        for (int w = 1; w < 16; ++w) {
            float mw = sm[w];
            bool gt = mw > M, eq = mw == M;
            C  = gt ? sc[w]  : (C  + (eq ? sc[w]  : 0.0f));
            SI = gt ? ssi[w] : (SI + (eq ? ssi[w] : 0.0f));
            SJ = gt ? ssj[w] : (SJ + (eq ? ssj[w] : 0.0f));
            M  = fmaxf(M, mw);
        }
        sxy[0] = SI / C;     // x = mean row index
        sxy[1] = SJ / C;     // y = mean col index
    }
    __syncthreads();
    const float x = sxy[0], y = sxy[1];
    const float Kc = -(float)WIMG * LN2;     // fold -ln2 into the weight

    // ---- Phase B: LDS-only weighted accumulation ----
    float acc = 0.0f;
    #pragma unroll
    for (int it = 0; it <= NIT; ++it) {
        if (it == NIT && !has_tail) break;
        int q = (it < NIT) ? (it * NT + tid) : qt;
        float2 b01 = __half22float2(bce_lds[q]);
        float2 b23 = __half22float2(bce_lds[NQ + q]);
        int i  = q / 56;
        int j0 = (q - i * 56) * 4;
        float di  = (float)i - x;
        float di2 = di * di;
        float bb[4] = {b01.x, b01.y, b23.x, b23.y};
        #pragma unroll
        for (int k = 0; k < 4; ++k) {
            float dj = (float)(j0 + k) - y;
            float s  = __builtin_amdgcn_sqrtf(di2 + dj * dj);
            float wf = Kc * __builtin_amdgcn_rcpf(s + 1.0f);   // -224*ln2/(sqrt+1)
            acc += wf * bb[k];
        }
    }

    // block sum reduce
    #pragma unroll
    for (int off = 32; off > 0; off >>= 1) acc += __shfl_down(acc, off);
    __shared__ float sred[16];
    if (lane == 0) sred[wid] = acc;
    __syncthreads();
    if (tid == 0) {
        float ssum = 0.0f;
        #pragma unroll
        for (int w = 0; w < 16; ++w) ssum += sred[w];
        atomicAdd(out, ssum * inv_total);
    }
}

extern "C" void kernel_launch(void* const* d_in, const int* in_sizes, int n_in,
                              void* d_out, int out_size, void* d_ws, size_t ws_size,
                              hipStream_t stream) {
    const float* input  = (const float*)d_in[0];
    const float* target = (const float*)d_in[1];
    float* out = (float*)d_out;
    // 98 KB dynamic LDS > 64 KB default cap — raise the attribute (host-side,
    // idempotent, graph-capture-safe: no stream interaction).
    hipFuncSetAttribute((const void*)floss_kernel,
                        hipFuncAttributeMaxDynamicSharedMemorySize, LDS_BYTES);
    // d_out is poisoned 0xAA before every call — zero the accumulator.
    hipMemsetAsync(out, 0, sizeof(float), stream);
    const float inv_total = 1.0f / (256.0f * 224.0f * 224.0f);
    floss_kernel<<<NB, NT, LDS_BYTES, stream>>>(input, target, out, inv_total);
}

// Round 9
// 122.235 us; speedup vs baseline: 1.0221x; 1.0221x over previous
//
#include <hip/hip_runtime.h>
#include <hip/hip_fp16.h>
#include <math.h>

// floss: weighted BCE with per-batch argmax-centroid weights.
// input/target: [256, 1, 224, 224] fp32. Output: scalar fp32 mean.
//
// R9: R7's single-memory-phase structure (bce2 is centroid-independent, so
// one 103 MB stream computes stats AND unweighted bce2 -> fp16 LDS; phase B
// is LDS-only) + MANUAL SOFTWARE PIPELINING. R7 was latency-bound (VALUBusy
// 29%, occ 38%, 1.2 TB/s, VGPR=36: compiler kept ~1 load in flight and
// serialized load->8xlog->pack->ds_write). Now: prefetch depth 2 on (t,p)
// float4 pairs + tail loads issued up-front => 3-5 vmem in flight/wave
// (need ~1.4/wave for 6.3 TB/s at 900-cyc latency). Quad-tree stats shorten
// the loop-carried chain (quad shares a row: si += fi*cq). launch_bounds
// without min-waves => VGPR cap 128, room for pipeline buffers (R5's spill
// was a 26-reg persistent array; these buffers are 3x8 + 8 regs).

#define WIMG 224
#define WW (WIMG * WIMG)        // 50176
#define NQ (WW / 4)             // 12544 quads; 56 quads/row
#define NB 256
#define NT 1024
#define NIT (NQ / NT)           // 12 full iterations
#define REM (NQ - NIT * NT)     // 256 tail quads
#define LDS_BYTES (2 * NQ * 4)  // 2 half2 per quad = 100352 B dynamic LDS
#define LN2 0.69314718055994530942f
#define CLAMP2 (-144.269504088896340736f)   // -100/ln2 (log2-domain clamp)

__device__ __forceinline__ float bce2_elem(float p, float t)
{
    float lp2  = fmaxf(__builtin_amdgcn_logf(p),        CLAMP2);
    float l1p2 = fmaxf(__builtin_amdgcn_logf(1.0f - p), CLAMP2);
    return l1p2 + t * (lp2 - l1p2);      // in [-13.3, 0] for these inputs
}

__global__ __launch_bounds__(NT) void floss_kernel(
    const float* __restrict__ input,
    const float* __restrict__ target,
    float* __restrict__ out,
    float inv_total)
{
    extern __shared__ __half2 bce_lds[];     // [0..NQ): e0,e1; [NQ..2NQ): e2,e3
    const int b   = blockIdx.x;
    const int tid = threadIdx.x;
    const float4* __restrict__ t4 = (const float4*)(target + (size_t)b * WW);
    const float4* __restrict__ p4 = (const float4*)(input  + (size_t)b * WW);

    // ---- tail loads issued up-front (independent, stay in flight) ----
    const bool has_tail = tid < REM;
    const int qt = NIT * NT + tid;           // tail quad (rows 219..223)
    float4 tvt = {}, pvt = {};
    if (has_tail) { tvt = t4[qt]; pvt = p4[qt]; }

    // ---- software-pipelined Phase A: prefetch depth 2 ----
    float m = -1.0f, cnt = 0.0f, si = 0.0f, sj = 0.0f;
    float4 tva = t4[tid],      pva = p4[tid];
    float4 tvb = t4[NT + tid], pvb = p4[NT + tid];
    #pragma unroll
    for (int it = 0; it < NIT; ++it) {
        // issue it+2's loads before consuming it's
        float4 tvn, pvn;
        if (it + 2 < NIT) { tvn = t4[(it + 2) * NT + tid]; pvn = p4[(it + 2) * NT + tid]; }
        float4 tv = tva, pv = pva;
        int q  = it * NT + tid;
        int i  = q / 56;
        int j0 = (q - i * 56) * 4;
        float fi = (float)i;

        // quad-tree stats (quad shares row i => si contribution = fi*cq)
        float mq  = fmaxf(fmaxf(tv.x, tv.y), fmaxf(tv.z, tv.w));
        float cq  = (tv.x == mq ? 1.0f : 0.0f) + (tv.y == mq ? 1.0f : 0.0f)
                  + (tv.z == mq ? 1.0f : 0.0f) + (tv.w == mq ? 1.0f : 0.0f);
        float sjq = (tv.x == mq ? (float)(j0 + 0) : 0.0f)
                  + (tv.y == mq ? (float)(j0 + 1) : 0.0f)
                  + (tv.z == mq ? (float)(j0 + 2) : 0.0f)
                  + (tv.w == mq ? (float)(j0 + 3) : 0.0f);
        float siq = fi * cq;
        bool gt = mq > m, eq = mq == m;
        cnt = gt ? cq  : (cnt + (eq ? cq  : 0.0f));
        si  = gt ? siq : (si  + (eq ? siq : 0.0f));
        sj  = gt ? sjq : (sj  + (eq ? sjq : 0.0f));
        m   = fmaxf(m, mq);

        // unweighted bce2 -> fp16 LDS
        bce_lds[q]      = __floats2half2_rn(bce2_elem(pv.x, tv.x), bce2_elem(pv.y, tv.y));
        bce_lds[NQ + q] = __floats2half2_rn(bce2_elem(pv.z, tv.z), bce2_elem(pv.w, tv.w));

        tva = tvb; pva = pvb;
        tvb = tvn; pvb = pvn;
    }
    if (has_tail) {
        int q  = qt;
        int i  = q / 56;
        int j0 = (q - i * 56) * 4;
        float fi = (float)i;
        float4 tv = tvt, pv = pvt;
        float mq  = fmaxf(fmaxf(tv.x, tv.y), fmaxf(tv.z, tv.w));
        float cq  = (tv.x == mq ? 1.0f : 0.0f) + (tv.y == mq ? 1.0f : 0.0f)
                  + (tv.z == mq ? 1.0f : 0.0f) + (tv.w == mq ? 1.0f : 0.0f);
        float sjq = (tv.x == mq ? (float)(j0 + 0) : 0.0f)
                  + (tv.y == mq ? (float)(j0 + 1) : 0.0f)
                  + (tv.z == mq ? (float)(j0 + 2) : 0.0f)
                  + (tv.w == mq ? (float)(j0 + 3) : 0.0f);
        float siq = fi * cq;
        bool gt = mq > m, eq = mq == m;
        cnt = gt ? cq  : (cnt + (eq ? cq  : 0.0f));
        si  = gt ? siq : (si  + (eq ? siq : 0.0f));
        sj  = gt ? sjq : (sj  + (eq ? sjq : 0.0f));
        m   = fmaxf(m, mq);
        bce_lds[q]      = __floats2half2_rn(bce2_elem(pv.x, tv.x), bce2_elem(pv.y, tv.y));
        bce_lds[NQ + q] = __floats2half2_rn(bce2_elem(pv.z, tv.z), bce2_elem(pv.w, tv.w));
    }

    // ---- argmax-stat reduction -> centroid (x, y) ----
    #pragma unroll
    for (int off = 32; off > 0; off >>= 1) {
        float m2  = __shfl_down(m,   off);
        float c2  = __shfl_down(cnt, off);
        float si2 = __shfl_down(si,  off);
        float sj2 = __shfl_down(sj,  off);
        bool gt = m2 > m, eq = m2 == m;
        cnt = gt ? c2  : (cnt + (eq ? c2  : 0.0f));
        si  = gt ? si2 : (si  + (eq ? si2 : 0.0f));
        sj  = gt ? sj2 : (sj  + (eq ? sj2 : 0.0f));
        m   = fmaxf(m, m2);
    }
    __shared__ float sm[16], sc[16], ssi[16], ssj[16];
    __shared__ float sxy[2];
    const int lane = tid & 63, wid = tid >> 6;
    if (lane == 0) { sm[wid] = m; sc[wid] = cnt; ssi[wid] = si; ssj[wid] = sj; }
    __syncthreads();
    if (tid == 0) {
        float M = sm[0], C = sc[0], SI = ssi[0], SJ = ssj[0];
        #pragma unroll
        for (int w = 1; w < 16; ++w) {
            float mw = sm[w];
            bool gt = mw > M, eq = mw == M;
            C  = gt ? sc[w]  : (C  + (eq ? sc[w]  : 0.0f));
            SI = gt ? ssi[w] : (SI + (eq ? ssi[w] : 0.0f));
            SJ = gt ? ssj[w] : (SJ + (eq ? ssj[w] : 0.0f));
            M  = fmaxf(M, mw);
        }
        sxy[0] = SI / C;     // x = mean row index
        sxy[1] = SJ / C;     // y = mean col index
    }
    __syncthreads();
    const float x = sxy[0], y = sxy[1];
    const float Kc = -(float)WIMG * LN2;     // fold -ln2 into the weight

    // ---- Phase B: LDS-only weighted accumulation ----
    float acc = 0.0f;
    #pragma unroll
    for (int it = 0; it <= NIT; ++it) {
        if (it == NIT && !has_tail) break;
        int q = (it < NIT) ? (it * NT + tid) : qt;
        float2 b01 = __half22float2(bce_lds[q]);
        float2 b23 = __half22float2(bce_lds[NQ + q]);
        int i  = q / 56;
        int j0 = (q - i * 56) * 4;
        float di  = (float)i - x;
        float di2 = di * di;
        float bb[4] = {b01.x, b01.y, b23.x, b23.y};
        #pragma unroll
        for (int k = 0; k < 4; ++k) {
            float dj = (float)(j0 + k) - y;
            float s  = __builtin_amdgcn_sqrtf(di2 + dj * dj);
            float wf = Kc * __builtin_amdgcn_rcpf(s + 1.0f);   // -224*ln2/(sqrt+1)
            acc += wf * bb[k];
        }
    }

    // block sum reduce
    #pragma unroll
    for (int off = 32; off > 0; off >>= 1) acc += __shfl_down(acc, off);
    __shared__ float sred[16];
    if (lane == 0) sred[wid] = acc;
    __syncthreads();
    if (tid == 0) {
        float ssum = 0.0f;
        #pragma unroll
        for (int w = 0; w < 16; ++w) ssum += sred[w];
        atomicAdd(out, ssum * inv_total);
    }
}

extern "C" void kernel_launch(void* const* d_in, const int* in_sizes, int n_in,
                              void* d_out, int out_size, void* d_ws, size_t ws_size,
                              hipStream_t stream) {
    const float* input  = (const float*)d_in[0];
    const float* target = (const float*)d_in[1];
    float* out = (float*)d_out;
    // 98 KB dynamic LDS > 64 KB default cap — raise the attribute (host-side,
    // idempotent, graph-capture-safe: no stream interaction).
    hipFuncSetAttribute((const void*)floss_kernel,
                        hipFuncAttributeMaxDynamicSharedMemorySize, LDS_BYTES);
    // d_out is poisoned 0xAA before every call — zero the accumulator.
    hipMemsetAsync(out, 0, sizeof(float), stream);
    const float inv_total = 1.0f / (256.0f * 224.0f * 224.0f);
    floss_kernel<<<NB, NT, LDS_BYTES, stream>>>(input, target, out, inv_total);
}